// Round 11
// baseline (275.201 us; speedup 1.0000x reference)
//
#include <hip/hip_runtime.h>
#include <cstdint>

#define NROWS 16384
#define FDIM 64
#define HDIM 128
#define ODIM 512
#define KDIM 8192   // FDIM * HDIM

#define BM 64
#define BN 512      // full O: elu computed once per A element (r10 win, kept)
#define BK 64
#define NST 128     // KDIM / BK

typedef short bf16x8 __attribute__((ext_vector_type(8)));
typedef float f32x4 __attribute__((ext_vector_type(4)));
typedef uint32_t u32x4 __attribute__((ext_vector_type(4)));

__device__ __forceinline__ uint16_t rne_bf16(float f) {
  uint32_t u = __builtin_bit_cast(uint32_t, f);
  u += 0x7fffu + ((u >> 16) & 1u);
  return (uint16_t)(u >> 16);
}

// ---- pre-kernel: W2 [K][O] f32 -> W2T [O][K] bf16.
// block(0,0): b2sum; block(1,0): bf16 copies of W1/b1. ----
__global__ void prep_w2t(const float* __restrict__ W2, uint16_t* __restrict__ W2T,
                         const float* __restrict__ b2, float* __restrict__ b2sum,
                         const float* __restrict__ W1, const float* __restrict__ b1,
                         uint16_t* __restrict__ w1bf, uint16_t* __restrict__ b1bf) {
  __shared__ float tile[64][65];
  const int k0 = blockIdx.x * 64;
  const int o0 = blockIdx.y * 64;
  const int tx = threadIdx.x;  // 0..63
  const int ty = threadIdx.y;  // 0..7
#pragma unroll
  for (int j = 0; j < 8; ++j)
    tile[ty + 8 * j][tx] = W2[(size_t)(k0 + ty + 8 * j) * ODIM + o0 + tx];
  __syncthreads();
#pragma unroll
  for (int j = 0; j < 8; ++j)
    W2T[(size_t)(o0 + ty + 8 * j) * KDIM + k0 + tx] = rne_bf16(tile[tx][ty + 8 * j]);
  const int t = ty * 64 + tx;  // 0..511
  if (blockIdx.x == 0 && blockIdx.y == 0) {
    float s = 0.f;
#pragma unroll
    for (int f = 0; f < FDIM; ++f) s += b2[(size_t)f * ODIM + t];
    b2sum[t] = s;
  } else if (blockIdx.x == 1 && blockIdx.y == 0) {
#pragma unroll
    for (int j = 0; j < 16; ++j) {  // 512*16 = 8192 = F*H
      w1bf[t * 16 + j] = rne_bf16(W1[t * 16 + j]);
      b1bf[t * 16 + j] = rne_bf16(b1[t * 16 + j]);
    }
  }
}

// operands for one k-step's A-staging (bf16: 17 regs; issued >=1 step before
// consumption, so the intervening __syncthreads drain makes them free)
struct Pref {
  u32x4 w1a, w1b, b1a, b1b;  // 16 bf16 W1 + 16 bf16 b1 (this thread's 16 cols)
  float xv;                  // x row ar
};

// ---- main fused kernel r11: 4 waves (256 thr) of 64x128 wave-tiles.
//
// r10 post-mortem: at 8 waves, per-CU-step = 3225cy vs pipe needs MFMA 1241 /
// LDS ~2150 / VALU ~1000; A-frags were read 8x (every wave spans all 64 rows).
// 4 waves of 64x128: A-redundancy 4x, frag reads 128->96/CU-step (LDS port
// ~1500cy), and the register wall moves: 2048/4 waves = 512 regs/wave, so
// acc[4][8]=128 + Pref 34 + frags 48 fits WITHOUT spill (r2-r7's 8-wave
// 128-acc could never fit). Cost: 1 wave/SIMD -> zero TLP; the matrix pipe
// must be filled by ILP (32 independent accs per kc chain MFMAs back-to-back).
//
// Session invariants kept: issue-early/consume-late (r9/r10), operand loads
// BEFORE glds (FIFO vmcnt), one barrier per k-step, no setprio.
__global__ __launch_bounds__(256)
__attribute__((amdgpu_waves_per_eu(1, 1))) void mlp_gemm(
    const float* __restrict__ x, const uint16_t* __restrict__ w1bf,
    const uint16_t* __restrict__ b1bf, const uint16_t* __restrict__ W2T,
    const float* __restrict__ b2sum, float* __restrict__ out) {
  __shared__ __align__(16) uint16_t As0[BM * BK];  // 8 KB each
  __shared__ __align__(16) uint16_t As1[BM * BK];
  __shared__ __align__(16) uint16_t Bs0[BN * BK];  // 64 KB each
  __shared__ __align__(16) uint16_t Bs1[BN * BK];

  const int tid = threadIdx.x;
  const int m0 = blockIdx.x * BM;  // grid 256 = 1 block/CU

  const int wid = tid >> 6;   // 0..3
  const int lane = tid & 63;
  const int wn = wid * 128;   // wave's n-slice (128 cols); all span BM=64 rows
  const int q = lane >> 4;    // quad
  const int r = lane & 15;

  // A-staging roles: thread -> row ar, col-groups {2c, 2c+1} (16 bf16)
  const int ar = tid >> 2;       // 0..63
  const int c = tid & 3;         // 0..3
  const int cbase = c * 16;      // first of this thread's 16 h-cols
  const int g0 = 2 * c, g1 = 2 * c + 1;
  const int aw0 = ar * BK + ((g0 ^ (ar & 7)) * 8);
  const int aw1 = ar * BK + ((g1 ^ (ar & 7)) * 8);
  // B-staging roles (glds: LDS dst = wave-uniform base + lane*16; swizzle
  // the GLOBAL col-group so fragment reads stay conflict-free)
  const int brow = lane >> 3;           // 0..7 within an 8-row chunk
  const int bcg = (lane & 7) ^ brow;    // swizzled col group

  f32x4 acc[4][8];
#pragma unroll
  for (int i = 0; i < 4; ++i)
#pragma unroll
    for (int j = 0; j < 8; ++j) acc[i][j] = {0.f, 0.f, 0.f, 0.f};

  // issue operand loads for k-step s (no waits here)
  auto ldops = [&](Pref& P, int s) {
    const int f = s >> 1;
    const int hoff = (s & 1) * 64 + cbase;
    P.w1a = *(const u32x4*)(w1bf + f * HDIM + hoff);
    P.w1b = *(const u32x4*)(w1bf + f * HDIM + hoff + 8);
    P.b1a = *(const u32x4*)(b1bf + f * HDIM + hoff);
    P.b1b = *(const u32x4*)(b1bf + f * HDIM + hoff + 8);
    P.xv = x[(size_t)(m0 + ar) * FDIM + f];
  };

  // issue the 16 async B chunks for k-step kk into Bb. chunk = wid*16+j ->
  // rows wid*128 + j*8 ..+8: each wave stages exactly its own n-slice.
  auto stageB = [&](uint16_t* Bb, int kk) {
#pragma unroll
    for (int j = 0; j < 16; ++j) {
      const int chunk = wid * 16 + j;  // 0..63
      const uint16_t* gp =
          W2T + (size_t)(chunk * 8 + brow) * KDIM + kk * BK + bcg * 8;
      uint16_t* lp = Bb + chunk * 512;  // wave-uniform base
      __builtin_amdgcn_global_load_lds(
          (const __attribute__((address_space(1))) uint32_t*)gp,
          (__attribute__((address_space(3))) uint32_t*)lp, 16, 0, 0);
    }
  };

  // elu(x*w1+b1) -> bf16 pack -> Ab: 16 elems (two 8-col groups), one row
  auto eluA = [&](uint16_t* Ab, const Pref& P) {
    auto grp = [&](u32x4 w1d, u32x4 b1d, int awo) {
      u32x4 ov;
#pragma unroll
      for (int p = 0; p < 4; ++p) {
        float wlo = __builtin_bit_cast(float, w1d[p] << 16);
        float whi = __builtin_bit_cast(float, w1d[p] & 0xffff0000u);
        float blo = __builtin_bit_cast(float, b1d[p] << 16);
        float bhi = __builtin_bit_cast(float, b1d[p] & 0xffff0000u);
        float plo = fmaf(P.xv, wlo, blo);
        float phi = fmaf(P.xv, whi, bhi);
        float elo = plo > 0.f ? plo : __expf(plo) - 1.f;
        float ehi = phi > 0.f ? phi : __expf(phi) - 1.f;
        ov[p] = __builtin_amdgcn_perm(__builtin_bit_cast(uint32_t, ehi),
                                      __builtin_bit_cast(uint32_t, elo),
                                      0x07060302u);
      }
      *(u32x4*)&Ab[awo] = ov;
    };
    grp(P.w1a, P.b1a, aw0);
    grp(P.w1b, P.b1b, aw1);
  };

  // compute: per kc, af[4] x bfr[8] -> 32 independent MFMAs (ILP fills pipe)
  auto compute = [&](const uint16_t* Ab, const uint16_t* Bb) {
#pragma unroll
    for (int kc = 0; kc < 2; ++kc) {
      bf16x8 af[4], bfr[8];
      const int cg = kc * 4 + q;
#pragma unroll
      for (int mt = 0; mt < 4; ++mt) {
        const int row = mt * 16 + r;  // m-range 0..63
        af[mt] = *(const bf16x8*)&Ab[row * BK + ((cg ^ (row & 7)) * 8)];
      }
#pragma unroll
      for (int nt = 0; nt < 8; ++nt) {
        const int row = wn + nt * 16 + r;  // o-range: wave's 128 cols
        bfr[nt] = *(const bf16x8*)&Bb[row * BK + ((cg ^ (row & 7)) * 8)];
      }
#pragma unroll
      for (int mt = 0; mt < 4; ++mt)
#pragma unroll
        for (int nt = 0; nt < 8; ++nt)
          acc[mt][nt] = __builtin_amdgcn_mfma_f32_16x16x32_bf16(
              af[mt], bfr[nt], acc[mt][nt], 0, 0, 0);
    }
  };

  Pref P0, P1;  // statically named ping-pong

  // ---- prologue: As0/Bs0 = step 0, P1 = ops(1) ----
  ldops(P0, 0);
  __builtin_amdgcn_sched_barrier(0);  // operand issue BEFORE the glds (FIFO)
  stageB(Bs0, 0);
  eluA(As0, P0);        // waits vmcnt(16): operands only, once
  ldops(P1, 1);
  __syncthreads();      // drains glds(0)

  // ---- steady state: one barrier per k-step ----
#pragma unroll 1
  for (int kk = 0; kk < NST - 2; kk += 2) {
    ldops(P0, kk + 2);                  // consumed next phase (free by then)
    __builtin_amdgcn_sched_barrier(0);
    stageB(Bs1, kk + 1);
    eluA(As1, P1);                      // zero wait (pre-barrier-drained)
    compute(As0, Bs0);
    __syncthreads();                    // glds(kk+1) ~2500cy old: cheap drain
    ldops(P1, kk + 3);                  // max NST-1 = 127: in bounds
    __builtin_amdgcn_sched_barrier(0);
    stageB(Bs0, kk + 2);
    eluA(As0, P0);
    compute(As1, Bs1);
    __syncthreads();
  }
  // exit: As0/Bs0 = step 126, P1 = ops(127)
  stageB(Bs1, NST - 1);
  eluA(As1, P1);
  compute(As0, Bs0);
  __syncthreads();
  compute(As1, Bs1);

  // ---- epilogue: + sum_f b2, * 1/sqrt(F) ----
  float bsv[8];
#pragma unroll
  for (int nt = 0; nt < 8; ++nt) bsv[nt] = b2sum[wn + nt * 16 + r];
#pragma unroll
  for (int mt = 0; mt < 4; ++mt)
#pragma unroll
    for (int nt = 0; nt < 8; ++nt)
#pragma unroll
      for (int v = 0; v < 4; ++v) {
        const int row = m0 + mt * 16 + q * 4 + v;  // C/D: row=(lane>>4)*4+reg
        const int col = wn + nt * 16 + r;          //      col=lane&15
        out[(size_t)row * ODIM + col] = (acc[mt][nt][v] + bsv[nt]) * 0.125f;
      }
}

extern "C" void kernel_launch(void* const* d_in, const int* in_sizes, int n_in,
                              void* d_out, int out_size, void* d_ws, size_t ws_size,
                              hipStream_t stream) {
  const float* x  = (const float*)d_in[0];
  const float* W1 = (const float*)d_in[1];
  const float* b1 = (const float*)d_in[2];
  const float* W2 = (const float*)d_in[3];
  const float* b2 = (const float*)d_in[4];
  float* out = (float*)d_out;

  char* ws = (char*)d_ws;
  float*    b2sum = (float*)ws;                       // 2KB
  uint16_t* w1bf  = (uint16_t*)(ws + 4096);           // 16KB
  uint16_t* b1bf  = (uint16_t*)(ws + 4096 + 16384);   // 16KB
  uint16_t* W2T   = (uint16_t*)(ws + 65536);          // 8MB [O][K] bf16

  prep_w2t<<<dim3(KDIM / 64, ODIM / 64), dim3(64, 8), 0, stream>>>(
      W2, W2T, b2, b2sum, W1, b1, w1bf, b1bf);
  mlp_gemm<<<NROWS / BM, 256, 0, stream>>>(x, w1bf, b1bf, W2T, b2sum, out);
}

// Round 12
// 246.680 us; speedup vs baseline: 1.1156x; 1.1156x over previous
//
#include <hip/hip_runtime.h>
#include <cstdint>

#define NROWS 16384
#define FDIM 64
#define HDIM 128
#define ODIM 512
#define KDIM 8192   // FDIM * HDIM

#define BM 64
#define BN 512      // full O: elu computed once per A element (r10 win)
#define BK 64
#define NST 128     // KDIM / BK

typedef short bf16x8 __attribute__((ext_vector_type(8)));
typedef float f32x4 __attribute__((ext_vector_type(4)));
typedef uint32_t u32x4 __attribute__((ext_vector_type(4)));

__device__ __forceinline__ uint16_t rne_bf16(float f) {
  uint32_t u = __builtin_bit_cast(uint32_t, f);
  u += 0x7fffu + ((u >> 16) & 1u);
  return (uint16_t)(u >> 16);
}

// ---- pre-kernel: W2 [K][O] f32 -> W2F, a bf16 copy in MFMA-FRAGMENT ORDER:
// for each (o-tile ot of 16, k-chunk kc of 32), 64 lanes x 16B contiguous:
//   W2F[(ot*256 + kc)*512 + lane*8 + e] = W2[kc*32 + (lane>>4)*8 + e][ot*16 + (lane&15)]
// so a wave's B-frag load is ONE fully-coalesced global_load_dwordx4 (1KB/instr).
// block(0,0) also computes b2sum.
__global__ void prep_w2f(const float* __restrict__ W2, uint16_t* __restrict__ W2F,
                         const float* __restrict__ b2, float* __restrict__ b2sum) {
  __shared__ float tile[64][65];
  const int k0 = blockIdx.x * 64;
  const int o0 = blockIdx.y * 64;
  const int tx = threadIdx.x;  // 0..63
  const int ty = threadIdx.y;  // 0..7
#pragma unroll
  for (int j = 0; j < 8; ++j)
    tile[ty + 8 * j][tx] = W2[(size_t)(k0 + ty + 8 * j) * ODIM + o0 + tx];  // tile[kl][ol]
  __syncthreads();
  // each thread emits one 16B lane-slot: o = o0+tx, k = k0 + ty*8 .. +8
  const int o = o0 + tx;
  u32x4 ov;
#pragma unroll
  for (int p = 0; p < 4; ++p) {
    const uint32_t lo = rne_bf16(tile[ty * 8 + 2 * p][tx]);
    const uint32_t hi = rne_bf16(tile[ty * 8 + 2 * p + 1][tx]);
    ov[p] = lo | (hi << 16);
  }
  const size_t idx = (size_t)(o >> 4) * 131072 + (size_t)((k0 >> 5) + (ty >> 2)) * 512 +
                     (size_t)(((o & 15) + 16 * (ty & 3)) * 8);
  *(u32x4*)&W2F[idx] = ov;

  if (blockIdx.x == 0 && blockIdx.y == 0) {
    const int t = ty * 64 + tx;  // 0..511
    float s = 0.f;
#pragma unroll
    for (int f = 0; f < FDIM; ++f) s += b2[(size_t)f * ODIM + t];
    b2sum[t] = s;
  }
}

// operands for one k-step's A-staging (f32 W1/b1: no unpack; 17 regs).
// Issued >=1 step before consumption -> the intervening barrier-drain makes
// them free to consume.
struct Pref {
  f32x4 wlo, whi, blo, bhi;
  float xv;
};

// ---- main fused kernel r12: r10 geometry/schedule, but B NEVER TOUCHES LDS.
//
// r11 post-mortem: B-staging rate was ~16-20 B/cyc/CU across r0/r9/r10/r11
// AND the guide's m97/m201 reference GEMMs -- the empirical global_load_lds
// path ceiling. It is not L2 BW (normal loads: ~60 B/cyc/CU, m56). Fix:
// read B-frags with coalesced global loads straight into MFMA operand regs
// (fragment-ordered W2F layout, 1KB/instr), LDS keeps only the tiny A tile.
//
// Invariants kept: 8 waves of 64x64 (acc=64, spill-free), issue-early ldops
// (FIFO: B loads issued FIRST each step so waiting on them leaves nothing
// stalled; P consumed next step after barrier drain), one barrier per step.
__global__ __launch_bounds__(512, 2) void mlp_gemm(
    const float* __restrict__ x, const float* __restrict__ W1,
    const float* __restrict__ b1, const uint16_t* __restrict__ W2F,
    const float* __restrict__ b2sum, float* __restrict__ out) {
  __shared__ __align__(16) uint16_t As0[BM * BK];  // 8 KB each (A only!)
  __shared__ __align__(16) uint16_t As1[BM * BK];

  const int tid = threadIdx.x;
  const int m0 = blockIdx.x * BM;  // grid 256 = 1 block/CU

  const int wid = tid >> 6;   // 0..7
  const int lane = tid & 63;
  const int wn = wid * 64;    // wave's n-slice; all waves span full BM=64 rows
  const int q = lane >> 4;    // quad
  const int r = lane & 15;

  // A-staging roles: thread -> row ar, col-group ac (8 bf16)
  const int ar = tid >> 3;  // 0..63
  const int ac = tid & 7;   // 0..7
  const int awc = (ac ^ (ar & 7)) * 8;

  // B fragment base: wave's 4 o-tiles start at ot = wid*4; lane offset *8
  const uint16_t* wbase = W2F + (size_t)(wid * 4) * 131072 + (size_t)lane * 8;

  f32x4 acc[4][4];
#pragma unroll
  for (int i = 0; i < 4; ++i)
#pragma unroll
    for (int j = 0; j < 4; ++j) acc[i][j] = {0.f, 0.f, 0.f, 0.f};

  // issue operand loads for k-step s (no waits here)
  auto ldops = [&](Pref& P, int s) {
    const int f = s >> 1;
    const int hoff = (s & 1) * 64 + ac * 8;
    const float* wp = W1 + (size_t)f * HDIM + hoff;
    const float* bp = b1 + (size_t)f * HDIM + hoff;
    P.wlo = *(const f32x4*)wp;
    P.whi = *(const f32x4*)(wp + 4);
    P.blo = *(const f32x4*)bp;
    P.bhi = *(const f32x4*)(bp + 4);
    P.xv = x[(size_t)(m0 + ar) * FDIM + f];
  };

  // issue the 8 B-frag loads for k-step kk (coalesced 1KB each, -> regs)
  auto ldB = [&](bf16x8* Bf, int kk) {
#pragma unroll
    for (int kc = 0; kc < 2; ++kc)
#pragma unroll
      for (int nt = 0; nt < 4; ++nt)
        Bf[kc * 4 + nt] =
            *(const bf16x8*)(wbase + ((size_t)nt * 256 + kk * 2 + kc) * 512);
  };

  // elu(x*w1+b1) -> bf16 pack -> Ab (one row/thread). P loaded >=1 step ago.
  auto eluA = [&](uint16_t* Ab, const Pref& P) {
    u32x4 ov;
#pragma unroll
    for (int p = 0; p < 4; ++p) {
      const float we0 = (p < 2) ? P.wlo[2 * p] : P.whi[2 * p - 4];
      const float we1 = (p < 2) ? P.wlo[2 * p + 1] : P.whi[2 * p - 3];
      const float be0 = (p < 2) ? P.blo[2 * p] : P.bhi[2 * p - 4];
      const float be1 = (p < 2) ? P.blo[2 * p + 1] : P.bhi[2 * p - 3];
      float plo = fmaf(P.xv, we0, be0);
      float phi = fmaf(P.xv, we1, be1);
      float elo = plo > 0.f ? plo : __expf(plo) - 1.f;
      float ehi = phi > 0.f ? phi : __expf(phi) - 1.f;
      ov[p] = __builtin_amdgcn_perm(__builtin_bit_cast(uint32_t, ehi),
                                    __builtin_bit_cast(uint32_t, elo),
                                    0x07060302u);
    }
    *(u32x4*)&Ab[ar * BK + awc] = ov;
  };

  // compute step: A-frags from LDS (XOR-swizzled), B-frags from regs
  auto compute = [&](const uint16_t* Ab, const bf16x8* Bf) {
#pragma unroll
    for (int kc = 0; kc < 2; ++kc) {
      bf16x8 af[4];
      const int cg = kc * 4 + q;
#pragma unroll
      for (int mt = 0; mt < 4; ++mt) {
        const int row = mt * 16 + r;
        af[mt] = *(const bf16x8*)&Ab[row * BK + ((cg ^ (row & 7)) * 8)];
      }
#pragma unroll
      for (int mt = 0; mt < 4; ++mt)
#pragma unroll
        for (int nt = 0; nt < 4; ++nt)
          acc[mt][nt] = __builtin_amdgcn_mfma_f32_16x16x32_bf16(
              af[mt], Bf[kc * 4 + nt], acc[mt][nt], 0, 0, 0);
    }
  };

  Pref Pa, Pb;          // statically named ping-pong
  bf16x8 Bf0[8], Bf1[8];  // per-half B frag regs (static indices only)

  // ---- prologue: As0 = A(0), Pa = ops(1) ----
  ldops(Pa, 0);
  eluA(As0, Pa);        // waits for Pa once
  ldops(Pa, 1);
  __syncthreads();      // As0 visible; Pa drained

  // ---- steady state: one barrier per k-step ----
  // invariant at loop top: As0 = A(kk), Pa = ops(kk+1)
#pragma unroll 1
  for (int kk = 0; kk < NST - 2; kk += 2) {
    ldB(Bf0, kk);                       // B(kk) -> regs (consumed below,
    ldops(Pb, kk + 2);                  //  covered by eluA+af reads)
    __builtin_amdgcn_sched_barrier(0);
    eluA(As1, Pa);                      // A(kk+1), zero wait
    compute(As0, Bf0);                  // step kk
    __syncthreads();
    ldB(Bf1, kk + 1);
    ldops(Pa, kk + 3);                  // max NST-1 = 127: in bounds
    __builtin_amdgcn_sched_barrier(0);
    eluA(As0, Pb);                      // A(kk+2)
    compute(As1, Bf1);                  // step kk+1
    __syncthreads();
  }
  // exit: As0 = A(NST-2), Pa = ops(NST-1)
  ldB(Bf0, NST - 2);
  __builtin_amdgcn_sched_barrier(0);
  eluA(As1, Pa);                        // A(NST-1)
  compute(As0, Bf0);                    // step NST-2
  __syncthreads();
  ldB(Bf1, NST - 1);
  compute(As1, Bf1);                    // step NST-1

  // ---- epilogue: + sum_f b2, * 1/sqrt(F) ----
  float bsv[4];
#pragma unroll
  for (int nt = 0; nt < 4; ++nt) bsv[nt] = b2sum[wn + nt * 16 + r];
#pragma unroll
  for (int mt = 0; mt < 4; ++mt)
#pragma unroll
    for (int nt = 0; nt < 4; ++nt)
#pragma unroll
      for (int v = 0; v < 4; ++v) {
        const int row = m0 + mt * 16 + q * 4 + v;  // C/D: row=(lane>>4)*4+reg
        const int col = wn + nt * 16 + r;          //      col=lane&15
        out[(size_t)row * ODIM + col] = (acc[mt][nt][v] + bsv[nt]) * 0.125f;
      }
}

extern "C" void kernel_launch(void* const* d_in, const int* in_sizes, int n_in,
                              void* d_out, int out_size, void* d_ws, size_t ws_size,
                              hipStream_t stream) {
  const float* x  = (const float*)d_in[0];
  const float* W1 = (const float*)d_in[1];
  const float* b1 = (const float*)d_in[2];
  const float* W2 = (const float*)d_in[3];
  const float* b2 = (const float*)d_in[4];
  float* out = (float*)d_out;

  char* ws = (char*)d_ws;
  float*    b2sum = (float*)ws;                 // 2KB
  uint16_t* W2F   = (uint16_t*)(ws + 65536);    // 8MB fragment-ordered bf16

  prep_w2f<<<dim3(KDIM / 64, ODIM / 64), dim3(64, 8), 0, stream>>>(W2, W2F, b2, b2sum);
  mlp_gemm<<<NROWS / BM, 512, 0, stream>>>(x, W1, b1, W2F, b2sum, out);
}

// Round 13
// 232.588 us; speedup vs baseline: 1.1832x; 1.0606x over previous
//
#include <hip/hip_runtime.h>
#include <cstdint>

#define NROWS 16384
#define FDIM 64
#define HDIM 128
#define ODIM 512
#define KDIM 8192   // FDIM * HDIM

#define BM 64
#define BN 512      // full O: elu computed once per A element (r10 win)
#define BK 64
#define NST 128     // KDIM / BK

typedef short bf16x8 __attribute__((ext_vector_type(8)));
typedef float f32x4 __attribute__((ext_vector_type(4)));
typedef uint32_t u32x4 __attribute__((ext_vector_type(4)));

__device__ __forceinline__ uint16_t rne_bf16(float f) {
  uint32_t u = __builtin_bit_cast(uint32_t, f);
  u += 0x7fffu + ((u >> 16) & 1u);
  return (uint16_t)(u >> 16);
}

// ---- pre-kernel: W2 [K][O] f32 -> W2F bf16 in MFMA-fragment order, K-MAJOR:
//   frag slot (kchunk 0..255, ot 0..31) at W2F[(kchunk*32 + ot)*512 + flane*8]
//   holds B-frag for o-tile ot, k = kchunk*32..+32; flane = (o&15) + 16*(k>>3 mod 4).
// K-major => each k-step's 64KB window is CONTIGUOUS: all in-phase blocks
// share one L2-resident window (streaming-friendly). block(0,0) also b2sum.
__global__ void prep_w2f(const float* __restrict__ W2, uint16_t* __restrict__ W2F,
                         const float* __restrict__ b2, float* __restrict__ b2sum) {
  __shared__ float tile[64][65];
  const int k0 = blockIdx.x * 64;
  const int o0 = blockIdx.y * 64;
  const int tx = threadIdx.x;  // 0..63
  const int ty = threadIdx.y;  // 0..7
#pragma unroll
  for (int j = 0; j < 8; ++j)
    tile[ty + 8 * j][tx] = W2[(size_t)(k0 + ty + 8 * j) * ODIM + o0 + tx];  // tile[kl][ol]
  __syncthreads();
  // thread emits one 16B flane slot: o = o0+tx, k = k0 + ty*8 .. +8
  const int o = o0 + tx;
  u32x4 ov;
#pragma unroll
  for (int p = 0; p < 4; ++p) {
    const uint32_t lo = rne_bf16(tile[ty * 8 + 2 * p][tx]);
    const uint32_t hi = rne_bf16(tile[ty * 8 + 2 * p + 1][tx]);
    ov[p] = lo | (hi << 16);
  }
  const size_t idx =
      ((size_t)((k0 >> 5) + (ty >> 2)) * 32 + (o >> 4)) * 512 +
      (size_t)(((o & 15) + 16 * (ty & 3)) * 8);
  *(u32x4*)&W2F[idx] = ov;

  if (blockIdx.x == 0 && blockIdx.y == 0) {
    const int t = ty * 64 + tx;  // 0..511
    float s = 0.f;
#pragma unroll
    for (int f = 0; f < FDIM; ++f) s += b2[(size_t)f * ODIM + t];
    b2sum[t] = s;
  }
}

// operands for one k-step's A-staging (f32 W1/b1; 17 regs, SINGLE buffer:
// consumed at phase start, re-loaded later the same phase)
struct Pref {
  f32x4 wlo, whi, blo, bhi;
  float xv;
};

// ---- main fused kernel r13: r12 structure + FULL-STEP register prefetch of B.
//
// r12 post-mortem: B-frags were issued and consumed in the SAME phase; only
// eluA (~350cy) covered an L2/HBM-mix latency of ~400-900cy -> ~900cy of
// unhidden latency per step (the session-constant ~3600cy/step was latency,
// not any pipe's bandwidth). Fix: B(t+1) loads issue right after eluA and are
// consumed a full phase later (cover = compute 1241cy + barrier + next eluA).
// Phase: eluA(P) -> issue ldB(B_next)+ldops(P,t+2) -> compute(cur: ZERO
// waits) -> barrier (drains loads issued ~1500cy ago; r9-proven cheap).
//
// Register budget (8 waves/CU => 256/wave cap): acc 64 + B0/B1 128 + P 17
// + af/addr ~30 = ~240. Tripwire: WRITE_SIZE >> 33MB = spill.
__global__ __launch_bounds__(512, 2) void mlp_gemm(
    const float* __restrict__ x, const float* __restrict__ W1,
    const float* __restrict__ b1, const uint16_t* __restrict__ W2F,
    const float* __restrict__ b2sum, float* __restrict__ out) {
  __shared__ __align__(16) uint16_t As0[BM * BK];  // 8 KB each (A only)
  __shared__ __align__(16) uint16_t As1[BM * BK];

  const int tid = threadIdx.x;
  const int m0 = blockIdx.x * BM;  // grid 256 = 1 block/CU

  const int wid = tid >> 6;   // 0..7
  const int lane = tid & 63;
  const int wn = wid * 64;    // wave's n-slice; all waves span full BM=64 rows
  const int q = lane >> 4;    // quad
  const int r = lane & 15;

  // A-staging roles: thread -> row ar, col-group ac (8 bf16)
  const int ar = tid >> 3;  // 0..63
  const int ac = tid & 7;   // 0..7
  const int awc = (ac ^ (ar & 7)) * 8;

  // B fragment base: wave's o-tiles are wid*4 .. wid*4+3; lane offset *8
  const uint16_t* wbase = W2F + (size_t)lane * 8;

  f32x4 acc[4][4];
#pragma unroll
  for (int i = 0; i < 4; ++i)
#pragma unroll
    for (int j = 0; j < 4; ++j) acc[i][j] = {0.f, 0.f, 0.f, 0.f};

  // issue operand loads for k-step s (no waits here)
  auto ldops = [&](Pref& P, int s) {
    const int f = s >> 1;
    const int hoff = (s & 1) * 64 + ac * 8;
    const float* wp = W1 + (size_t)f * HDIM + hoff;
    const float* bp = b1 + (size_t)f * HDIM + hoff;
    P.wlo = *(const f32x4*)wp;
    P.whi = *(const f32x4*)(wp + 4);
    P.blo = *(const f32x4*)bp;
    P.bhi = *(const f32x4*)(bp + 4);
    P.xv = x[(size_t)(m0 + ar) * FDIM + f];
  };

  // issue the 8 B-frag loads for k-step kk (k-major W2F: one 64KB window)
  auto ldB = [&](bf16x8* Bf, int kk) {
#pragma unroll
    for (int kc = 0; kc < 2; ++kc)
#pragma unroll
      for (int nt = 0; nt < 4; ++nt)
        Bf[kc * 4 + nt] = *(const bf16x8*)(
            wbase + ((size_t)(kk * 2 + kc) * 32 + wid * 4 + nt) * 512);
  };

  // elu(x*w1+b1) -> bf16 pack -> Ab (one row/thread). P loaded >=1 phase ago.
  auto eluA = [&](uint16_t* Ab, const Pref& P) {
    u32x4 ov;
#pragma unroll
    for (int p = 0; p < 4; ++p) {
      const float we0 = (p < 2) ? P.wlo[2 * p] : P.whi[2 * p - 4];
      const float we1 = (p < 2) ? P.wlo[2 * p + 1] : P.whi[2 * p - 3];
      const float be0 = (p < 2) ? P.blo[2 * p] : P.bhi[2 * p - 4];
      const float be1 = (p < 2) ? P.blo[2 * p + 1] : P.bhi[2 * p - 3];
      float plo = fmaf(P.xv, we0, be0);
      float phi = fmaf(P.xv, we1, be1);
      float elo = plo > 0.f ? plo : __expf(plo) - 1.f;
      float ehi = phi > 0.f ? phi : __expf(phi) - 1.f;
      ov[p] = __builtin_amdgcn_perm(__builtin_bit_cast(uint32_t, ehi),
                                    __builtin_bit_cast(uint32_t, elo),
                                    0x07060302u);
    }
    *(u32x4*)&Ab[ar * BK + awc] = ov;
  };

  // compute step: A-frags from LDS (XOR-swizzled), B-frags from regs (no waits)
  auto compute = [&](const uint16_t* Ab, const bf16x8* Bf) {
#pragma unroll
    for (int kc = 0; kc < 2; ++kc) {
      const int cg = kc * 4 + q;
#pragma unroll
      for (int mt = 0; mt < 4; ++mt) {
        const int row = mt * 16 + r;
        const bf16x8 af = *(const bf16x8*)&Ab[row * BK + ((cg ^ (row & 7)) * 8)];
#pragma unroll
        for (int nt = 0; nt < 4; ++nt)
          acc[mt][nt] = __builtin_amdgcn_mfma_f32_16x16x32_bf16(
              af, Bf[kc * 4 + nt], acc[mt][nt], 0, 0, 0);
      }
    }
  };

  Pref P;                 // single buffer: consumed at phase start, reloaded after
  bf16x8 B0[8], B1[8];    // full-step B double-buffer (static indices only)

  // ---- prologue: As0 = A(0), B0 = B(0), P = ops(1) ----
  ldops(P, 0);            // issued FIRST (FIFO: waiting on P won't drain B0)
  ldB(B0, 0);
  eluA(As0, P);           // waits for P once
  ldops(P, 1);
  __syncthreads();        // As0 visible; B0 + P(1) drained

  // ---- steady state: one barrier per k-step; 2 phases/iter ----
  // invariant at loop top: As0 = A(kk), B0 = B(kk), P = ops(kk+1)
#pragma unroll 1
  for (int kk = 0; kk < NST - 2; kk += 2) {
    // phase A (step kk)
    eluA(As1, P);                       // A(kk+1): zero wait
    ldB(B1, kk + 1);                    // full-phase cover
    ldops(P, kk + 2);
    __builtin_amdgcn_sched_barrier(0);
    compute(As0, B0);                   // zero memory waits
    __syncthreads();                    // drains B1 + P (issued ~1500cy ago)
    // phase B (step kk+1)
    eluA(As0, P);                       // A(kk+2)
    ldB(B0, kk + 2);
    ldops(P, kk + 3);                   // max = NST-1 = 127: in bounds
    __builtin_amdgcn_sched_barrier(0);
    compute(As1, B1);
    __syncthreads();
  }
  // exit: As0 = A(NST-2), B0 = B(NST-2), P = ops(NST-1)
  eluA(As1, P);                         // A(NST-1)
  ldB(B1, NST - 1);
  __builtin_amdgcn_sched_barrier(0);
  compute(As0, B0);                     // step NST-2
  __syncthreads();
  compute(As1, B1);                     // step NST-1

  // ---- epilogue: + sum_f b2, * 1/sqrt(F) ----
  float bsv[4];
#pragma unroll
  for (int nt = 0; nt < 4; ++nt) bsv[nt] = b2sum[wn + nt * 16 + r];
#pragma unroll
  for (int mt = 0; mt < 4; ++mt)
#pragma unroll
    for (int nt = 0; nt < 4; ++nt)
#pragma unroll
      for (int v = 0; v < 4; ++v) {
        const int row = m0 + mt * 16 + q * 4 + v;  // C/D: row=(lane>>4)*4+reg
        const int col = wn + nt * 16 + r;          //      col=lane&15
        out[(size_t)row * ODIM + col] = (acc[mt][nt][v] + bsv[nt]) * 0.125f;
      }
}

extern "C" void kernel_launch(void* const* d_in, const int* in_sizes, int n_in,
                              void* d_out, int out_size, void* d_ws, size_t ws_size,
                              hipStream_t stream) {
  const float* x  = (const float*)d_in[0];
  const float* W1 = (const float*)d_in[1];
  const float* b1 = (const float*)d_in[2];
  const float* W2 = (const float*)d_in[3];
  const float* b2 = (const float*)d_in[4];
  float* out = (float*)d_out;

  char* ws = (char*)d_ws;
  float*    b2sum = (float*)ws;                 // 2KB
  uint16_t* W2F   = (uint16_t*)(ws + 65536);    // 8MB fragment-ordered bf16

  prep_w2f<<<dim3(KDIM / 64, ODIM / 64), dim3(64, 8), 0, stream>>>(W2, W2F, b2, b2sum);
  mlp_gemm<<<NROWS / BM, 512, 0, stream>>>(x, W1, b1, W2F, b2sum, out);
}